// Round 9
// baseline (149.592 us; speedup 1.0000x reference)
//
#include <hip/hip_runtime.h>

// Problem: B=2048, D=2048, N=64 transforms, R=32.
//  out0 (2048x2048 f32) = sum_n gate[b,n] * (x V_n^T U_n^T)
//  out1 (2048x64  f32) = jumprelu(x enc^T - bias)
//  out2 (64 f32)       = ||U_n||_F ||V_n||_F / 256
// Flatten (n,r)->c=2048: two 2048^3 bf16 MFMA GEMMs.
// R15->R16: attack the LDS-read-issue bound. Model: per K-step per CU,
// 8 waves x 24 ds_read_b128 x 12cy = 2304cy LDS-pipe vs ~310cy MFMA/SIMD
// => K-loop time ~= LDS issue. Reads/step = wave-tile perimeter/1KB, so
// 4 waves x 64x64 tiles (WGM=WGN=2, MI=NJ=4, 256 thr) cut reads/FLOP
// 1.5x: per-CU LDS occupancy 2304 -> 1536 cy/step. Risk: 1 wave/SIMD.
// Swizzle algebra survives VW=4 (key (w&3)*4+lrow4 exact). Fused gate:
// wave wn handles slices s in {2wn,2wn+1}; epilogue reduces 2 partials,
// per-j gate n=2wn+(j>>1). Main-GEMM accumulation order unchanged.

#define D_MODEL 2048
#define BATCH   2048
#define NT      64
#define RANK    32

typedef __attribute__((ext_vector_type(8))) __bf16 bf16x8;
typedef __attribute__((ext_vector_type(4))) float  f32x4;
typedef __attribute__((ext_vector_type(8))) unsigned short ushort8;

__device__ __forceinline__ unsigned short f2bf(float f) {
  unsigned int u = __builtin_bit_cast(unsigned int, f);
  u += 0x7FFFu + ((u >> 16) & 1u);          // RNE
  return (unsigned short)(u >> 16);
}

// async global->LDS, 16B per lane. LDS dest is wave-uniform base + lane*16.
__device__ __forceinline__ void gload_lds16(const void* g, void* l) {
  __builtin_amdgcn_global_load_lds(
      (const __attribute__((address_space(1))) unsigned int*)g,
      (__attribute__((address_space(3))) unsigned int*)l,
      16, 0, 0);
}

// wait until <=N vector-memory ops outstanding, then workgroup barrier.
// Single asm block: no memory op can be scheduled between wait and barrier.
template <int N>
__device__ __forceinline__ void vm_wait_barrier() {
  if constexpr (N == 0)
    asm volatile("s_waitcnt vmcnt(0)\ns_barrier" ::: "memory");
  else if constexpr (N == 16)
    asm volatile("s_waitcnt vmcnt(16)\ns_barrier" ::: "memory");
  else if constexpr (N == 17)
    asm volatile("s_waitcnt vmcnt(17)\ns_barrier" ::: "memory");
  else
    static_assert(N == 0 || N == 16 || N == 17, "add vmcnt case");
}

// ---------------- merged prep ----------------
// blocks [0,1024): x->bf16   [1024,1152): enc->bf16
// blocks [1152,1408): V->bf16 (+sumsq)   [1408,1664): U->Ut bf16 (+sumsq)

__device__ __forceinline__ void block_reduce_store(float ss, float* dst, int slot) {
  __shared__ float red[256];
  int t = threadIdx.x;
  red[t] = ss;
  __syncthreads();
  for (int s = 128; s > 0; s >>= 1) {
    if (t < s) red[t] += red[t + s];
    __syncthreads();
  }
  if (t == 0) dst[slot] = red[0];
}

__global__ void k_prep(const float4* __restrict__ x, const float4* __restrict__ enc,
                       const float4* __restrict__ V, const float4* __restrict__ U,
                       ushort4* __restrict__ xb, ushort4* __restrict__ encb,
                       ushort4* __restrict__ Vb, unsigned short* __restrict__ Ut,
                       float* __restrict__ partV, float* __restrict__ partU) {
  int bid = blockIdx.x, t = threadIdx.x;
  if (bid < 1024) {                      // x: 1024 float4/block, ushort8 stores
#pragma unroll
    for (int it = 0; it < 2; ++it) {
      size_t i2 = (size_t)(it * 256 + t) * 2;          // pair of float4
      size_t idx = (size_t)bid * 1024 + i2;
      float4 v0 = x[idx];
      float4 v1 = x[idx + 1];
      ushort8 o;
      o[0] = f2bf(v0.x); o[1] = f2bf(v0.y); o[2] = f2bf(v0.z); o[3] = f2bf(v0.w);
      o[4] = f2bf(v1.x); o[5] = f2bf(v1.y); o[6] = f2bf(v1.z); o[7] = f2bf(v1.w);
      ((ushort8*)xb)[(size_t)bid * 512 + it * 256 + t] = o;
    }
  } else if (bid < 1152) {               // enc: 32768 float4
    int i = (bid - 1024) * 256 + t;
    float4 v = enc[i];
    ushort4 o;
    o.x = f2bf(v.x); o.y = f2bf(v.y); o.z = f2bf(v.z); o.w = f2bf(v.w);
    encb[i] = o;
  } else if (bid < 1408) {               // V: convert + sumsq, ushort8 stores
    int b = bid - 1152;                  // 256 blocks: n=b>>2, quarter=b&3
    size_t base4 = (size_t)b * 4096;
    float ss = 0.f;
    for (int it = 0; it < 8; ++it) {
      size_t i2 = (size_t)(it * 256 + t) * 2;          // pair of float4
      size_t idx = base4 + i2;
      float4 v0 = V[idx];
      float4 v1 = V[idx + 1];
      ss += v0.x * v0.x + v0.y * v0.y + v0.z * v0.z + v0.w * v0.w;
      ss += v1.x * v1.x + v1.y * v1.y + v1.z * v1.z + v1.w * v1.w;
      ushort8 o;
      o[0] = f2bf(v0.x); o[1] = f2bf(v0.y); o[2] = f2bf(v0.z); o[3] = f2bf(v0.w);
      o[4] = f2bf(v1.x); o[5] = f2bf(v1.y); o[6] = f2bf(v1.z); o[7] = f2bf(v1.w);
      ((ushort8*)Vb)[base4 / 2 + it * 256 + t] = o;
    }
    block_reduce_store(ss, partV, b);
  } else {                               // U: transpose-convert + sumsq, 16B stores
    int b = bid - 1408;
    int n = b >> 2;
    size_t base4 = (size_t)b * 4096;
    float ss = 0.f;
    for (int it = 0; it < 8; ++it) {
      size_t i2 = (size_t)(it * 256 + t) * 2;     // pair of consecutive float4
      size_t idx4 = base4 + i2;
      float4 v0 = U[idx4];
      float4 v1 = U[idx4 + 1];
      ss += v0.x * v0.x + v0.y * v0.y + v0.z * v0.z + v0.w * v0.w;
      ss += v1.x * v1.x + v1.y * v1.y + v1.z * v1.z + v1.w * v1.w;
      size_t e = idx4 * 4 - (size_t)n * (D_MODEL * RANK);  // elem offset in transform
      int dcol = (int)(e >> 5);
      int r = (int)(e & 31);              // 0,8,16,24 -> 16B aligned
      ushort8 o;
      o[0] = f2bf(v0.x); o[1] = f2bf(v0.y); o[2] = f2bf(v0.z); o[3] = f2bf(v0.w);
      o[4] = f2bf(v1.x); o[5] = f2bf(v1.y); o[6] = f2bf(v1.z); o[7] = f2bf(v1.w);
      *(ushort8*)(Ut + (size_t)dcol * 2048 + n * 32 + r) = o;
    }
    block_reduce_store(ss, partU, b);
  }
}

// ---------------- GEMM (BK=128, XOR-swizzled LDS, counted-vmcnt dbuf) -----
// A: M x K row-major bf16. Bt: N x K row-major bf16. VW = WGM*WGN = 4
// waves, 64x64 wave tiles (MI=NJ=4). Row = 256B = 16 chunks of 16B;
// logical chunk cl at physical cl^(row&15); staging key = (w&3)*4+lrow4.
// Pipeline depth 2, counted vmcnt (never 0 in main loop).
// EPI 0 (fused gate, WGM=2 WGN=2 MI=4 NJ=4): stage() adds a 4x128 enc
//   tile (1KB, all waves duplicate-load, LPW=17). Wave wn accumulates
//   gate pre-acts over slices s in {2wn, 2wn+1}; epilogue LDS-reduces the
//   2 partials, per-j gate index n = 2wn + (j>>1), writes out1 + gated Y.
//   Block 0 finishes frob.
// EPI 1: outF[row*2048+col] = acc   (plain f32 store)
template <int WGM, int WGN, int MI, int NJ, int EPI, int SWZ>
__global__ __launch_bounds__(WGM * WGN * 64, (WGM * WGN == 4) ? 1 : 2)
void gemm_bt(const unsigned short* __restrict__ A,
             const unsigned short* __restrict__ Bt,
             unsigned short* __restrict__ outB,
             float* __restrict__ outF, int K, int klen,
             const unsigned short* __restrict__ Eb,
             const float* __restrict__ bias,
             const float* __restrict__ pU, const float* __restrict__ pV,
             float* __restrict__ frob, float* __restrict__ gateOut) {
  constexpr int VW = WGM * WGN;           // waves per block (multiple of 4)
  constexpr int BM = WGM * MI * 16;
  constexpr int BN = WGN * NJ * 16;
  constexpr int BK = 128;
  constexpr int GA = BM / (4 * VW);       // A stage instrs per wave per tile
  constexpr int GB = BN / (4 * VW);
  constexpr int LPW = GA + GB + (EPI == 0 ? 1 : 0);
  constexpr int HBUF = (BM + BN) * BK;    // shorts per buffer
  constexpr int ENCS = (EPI == 0) ? 512 : 0;  // shorts per enc buffer
  static_assert(EPI != 0 || (WGM == 2 && WGN == 2 && MI == 4 && NJ == 4),
                "EPI0 fused-gate layout requires 2x2 waves, MI=4, NJ=4");
  __shared__ __align__(16) unsigned short smem[2 * HBUF + 2 * ENCS];

  const int tid = threadIdx.x;
  const int w = tid >> 6;
  const int lane = tid & 63;
  const int quad = lane >> 4;
  const int l15 = lane & 15;
  const int wm = w % WGM;
  const int wn = w / WGM;

  int blockM, blockN;
  if constexpr (SWZ) {
    // grid.x = 256 = 16 (M/128) x 16 (N/128) tiles; lin%8 -> XCD,
    // each XCD owns a contiguous 4M x 8N tile region.
    const int lin = blockIdx.x;
    const int xcd = lin & 7;
    const int i = lin >> 3;              // 0..31 within XCD
    blockM = (xcd & 3) * 4 + (i & 3);    // [0,16)
    blockN = (xcd >> 2) * 8 + (i >> 2);  // [0,16)
  } else {
    blockN = blockIdx.x;
    blockM = blockIdx.y;
  }

  if constexpr (EPI == 0) {              // frob finish (inputs ready post-prep)
    if (blockIdx.x == 0 && tid < NT) {
      float su = pU[4 * tid] + pU[4 * tid + 1] + pU[4 * tid + 2] + pU[4 * tid + 3];
      float sv = pV[4 * tid] + pV[4 * tid + 1] + pV[4 * tid + 2] + pV[4 * tid + 3];
      frob[tid] = sqrtf(su) * sqrtf(sv) * (1.0f / 256.0f);
    }
  }

  // staging: instr (j,w) covers rows (j*VW+w)*4 + lrow4; key = row&15 =
  // (w&3)*4 + lrow4 (VW==4: (j*4+w)&3 == w). Pre-swizzled source chunk lq.
  const int lrow4 = lane >> 4;
  const int key = ((w & 3) << 2) | lrow4;
  const int lq = l15 ^ key;
  const unsigned short* Ag = A + (size_t)(blockM * BM + w * 4 + lrow4) * K + lq * 8;
  const unsigned short* Bg = Bt + (size_t)(blockN * BN + w * 4 + lrow4) * K + lq * 8;
  // enc tile source: lane l covers n = bn*4 + (l>>4), k-chunk (l&15)*8
  const unsigned short* Eg = (EPI == 0)
      ? Eb + (size_t)(blockN * 4 + lrow4) * K + l15 * 8 : nullptr;

  // fragment rows rf have rf&15 == l15; physical chunk = (s*4+quad) ^ l15
  const int rfA = wm * MI * 16 + l15;
  const int rfB = wn * NJ * 16 + l15;

  f32x4 acc[MI][NJ];
  f32x4 acc_g[MI];
  const f32x4 z = {0.f, 0.f, 0.f, 0.f};
#pragma unroll
  for (int i = 0; i < MI; ++i) {
    acc_g[i] = z;
#pragma unroll
    for (int j = 0; j < NJ; ++j) acc[i][j] = z;
  }

  auto stage = [&](int buf, int k0) {
    unsigned short* As = smem + buf * HBUF;
    unsigned short* Bs = As + BM * BK;
#pragma unroll
    for (int j = 0; j < GA; ++j)
      gload_lds16(Ag + (size_t)(j * VW * 4) * K + k0,
                  (char*)As + (j * VW + w) * 1024);
#pragma unroll
    for (int j = 0; j < GB; ++j)
      gload_lds16(Bg + (size_t)(j * VW * 4) * K + k0,
                  (char*)Bs + (j * VW + w) * 1024);
    if constexpr (EPI == 0)              // all waves write same bytes: benign
      gload_lds16(Eg + k0, (char*)(smem + 2 * HBUF + buf * ENCS));
  };

  // prologue: stage K-tile 0 into buffer 0
  stage(0, 0);

  const int nt = klen / BK;
  int cur = 0;
  for (int t = 0; t < nt; ++t) {
    if (t + 1 < nt) {
      stage(cur ^ 1, (t + 1) * BK);      // issue next tile's loads
      vm_wait_barrier<LPW>();            // tile t landed; t+1 in flight
    } else {
      vm_wait_barrier<0>();              // last tile: drain
    }
    const unsigned short* As = smem + cur * HBUF;
    const unsigned short* Bs = As + BM * BK;
    const unsigned short* Es = smem + 2 * HBUF + cur * ENCS;
#pragma unroll
    for (int s = 0; s < 4; ++s) {
      bf16x8 af[MI], bfr[NJ];
#pragma unroll
      for (int i = 0; i < MI; ++i)
        af[i] = *(const bf16x8*)((const char*)As + (rfA + i * 16) * 256 +
                                 (((s * 4 + quad) ^ l15) << 4));
#pragma unroll
      for (int j = 0; j < NJ; ++j)
        bfr[j] = *(const bf16x8*)((const char*)Bs + (rfB + j * 16) * 256 +
                                  (((s * 4 + quad) ^ l15) << 4));
      if constexpr (EPI == 0) {
        if ((s >> 1) == wn) {            // wave-uniform: slices {2wn, 2wn+1}
          bf16x8 be = *(const bf16x8*)((const char*)Es +
                                       ((l15 & 3) * 128 + s * 32 + quad * 8) * 2);
#pragma unroll
          for (int i = 0; i < MI; ++i)
            acc_g[i] = __builtin_amdgcn_mfma_f32_16x16x32_bf16(af[i], be, acc_g[i], 0, 0, 0);
        }
      }
#pragma unroll
      for (int i = 0; i < MI; ++i)
#pragma unroll
        for (int j = 0; j < NJ; ++j)
          acc[i][j] = __builtin_amdgcn_mfma_f32_16x16x32_bf16(af[i], bfr[j], acc[i][j], 0, 0, 0);
    }
    // protect buffer reuse: next iter stages into the buffer just read.
    asm volatile("s_barrier" ::: "memory");
    cur ^= 1;
  }

  // epilogue: C/D layout col=lane&15, row=quad*4+reg
  const int row0 = blockM * BM + wm * MI * 16 + quad * 4;
  const int col0 = blockN * BN + wn * NJ * 16 + l15;
  if constexpr (EPI == 0) {
    // cross-wn reduce of gate partials: tmp[wn'][wm][i][row16][nl4] f32
    // (4KB; staging LDS dead after final barrier).
    float* tmp = (float*)smem;
    if (l15 < 4) {
#pragma unroll
      for (int i = 0; i < MI; ++i)
#pragma unroll
        for (int r = 0; r < 4; ++r)
          tmp[(((wn * 2 + wm) * MI + i) * 16 + quad * 4 + r) * 4 + l15] = acc_g[i][r];
    }
    __syncthreads();
    const float bv0 = bias[blockN * 4 + 2 * wn];
    const float bv1 = bias[blockN * 4 + 2 * wn + 1];
#pragma unroll
    for (int i = 0; i < MI; ++i) {
#pragma unroll
      for (int t = 0; t < 4; ++t) {
        const int r0 = (((0 * 2 + wm) * MI + i) * 16 + quad * 4 + t) * 4;
        const int r1 = (((1 * 2 + wm) * MI + i) * 16 + quad * 4 + t) * 4;
        float p0 = tmp[r0 + 2 * wn] + tmp[r1 + 2 * wn];
        float p1 = tmp[r0 + 2 * wn + 1] + tmp[r1 + 2 * wn + 1];
        float pre0 = p0 - bv0, pre1 = p1 - bv1;
        float g0 = pre0 > 0.f ? pre0 : 0.f;
        float g1 = pre1 > 0.f ? pre1 : 0.f;
        const int row = row0 + i * 16 + t;
        if (l15 == 0) {                   // unique (row, n) owner writes out1
          gateOut[(size_t)row * NT + blockN * 4 + 2 * wn]     = g0;
          gateOut[(size_t)row * NT + blockN * 4 + 2 * wn + 1] = g1;
        }
#pragma unroll
        for (int j = 0; j < NJ; ++j)
          outB[(size_t)row * 2048 + col0 + j * 16] =
              f2bf(acc[i][j][t] * (j < 2 ? g0 : g1));
      }
    }
  } else {
#pragma unroll
    for (int i = 0; i < MI; ++i) {
#pragma unroll
      for (int j = 0; j < NJ; ++j) {
        const int col = col0 + j * 16;
#pragma unroll
        for (int t = 0; t < 4; ++t) {
          const int row = row0 + i * 16 + t;
          outF[(size_t)row * 2048 + col] = acc[i][j][t];
        }
      }
    }
  }
}

// ---------------- launch ----------------

extern "C" void kernel_launch(void* const* d_in, const int* in_sizes, int n_in,
                              void* d_out, int out_size, void* d_ws, size_t ws_size,
                              hipStream_t stream) {
  const float* x    = (const float*)d_in[0];
  const float* V    = (const float*)d_in[1];
  const float* U    = (const float*)d_in[2];
  const float* enc  = (const float*)d_in[3];
  const float* bias = (const float*)d_in[4];

  float* out  = (float*)d_out;                        // 2048*2048
  float* gate = out + (size_t)BATCH * D_MODEL;        // 2048*64
  float* frob = gate + (size_t)BATCH * NT;            // 64

  char* ws = (char*)d_ws;                             // ~33 MB used
  unsigned short* xb   = (unsigned short*)(ws);                     // 8 MB
  unsigned short* Vb   = (unsigned short*)(ws + (8u << 20));        // 8 MB
  unsigned short* Ut   = (unsigned short*)(ws + (16u << 20));       // 8 MB
  unsigned short* Yg   = (unsigned short*)(ws + (24u << 20));       // 8 MB
  unsigned short* encb = (unsigned short*)(ws + (32u << 20));       // 256 KB
  float* partU = (float*)(ws + (32u << 20) + 262144);
  float* partV = partU + 256;

  // prep: all bf16 conversions + U transpose + Frobenius partials
  k_prep<<<1664, 256, 0, stream>>>((const float4*)x, (const float4*)enc,
                                   (const float4*)V, (const float4*)U,
                                   (ushort4*)xb, (ushort4*)encb, (ushort4*)Vb, Ut,
                                   partV, partU);

  // G1' = fused: Yg = bf16(gate .* (x @ Vflat^T)), gate/out1, frob.
  // 128x128 tiles BK=128, 4 waves (64x64 wave tiles), 256 blocks (1/CU),
  // XCD-swizzled, counted-vmcnt depth-2 pipeline.
  gemm_bt<2, 2, 4, 4, 0, 1><<<dim3(256, 1, 1), 256, 0, stream>>>(
      xb, Vb, Yg, nullptr, D_MODEL, D_MODEL,
      encb, bias, partU, partV, frob, gate);

  // G2: out = Yg @ Ut^T: 2048^3, fp32 store, same GEMM structure
  gemm_bt<2, 2, 4, 4, 1, 1><<<dim3(256, 1, 1), 256, 0, stream>>>(
      Yg, Ut, nullptr, out, D_MODEL, D_MODEL,
      nullptr, nullptr, nullptr, nullptr, nullptr, nullptr);
}

// Round 10
// 145.410 us; speedup vs baseline: 1.0288x; 1.0288x over previous
//
#include <hip/hip_runtime.h>

// Problem: B=2048, D=2048, N=64 transforms, R=32.
//  out0 (2048x2048 f32) = sum_n gate[b,n] * (x V_n^T U_n^T)
//  out1 (2048x64  f32) = jumprelu(x enc^T - bias)
//  out2 (64 f32)       = ||U_n||_F ||V_n||_F / 256
// Flatten (n,r)->c=2048: two 2048^3 bf16 MFMA GEMMs:
//   Y[b,c]   = x @ Vflat^T          (V already B^T-layout)
//   out[b,d] = (Y .* gate) @ Ut^T   (Ut[d,c] = U[n,d,r] pre-transposed)
// R16->R17: REVERT to R13 (measured best, 145.5us). R16's 4-wave 64x64
// tiles regressed +4.1us: the 1.5x ds_read-issue cut was consumed by
// 1-wave/SIMD latency exposure. Ceiling accounting: ~85us fixed harness
// fills (R12 attribution), prep ~13us vs 11.5 floor (2 null vectorization
// attempts), G1'+G2 ~44us = 818 TF at N=2048 (~33% dense peak; composed
// floor ~40us; 6 schedule variants null), gaps ~3us (mega-kernel fusion
// regressed 2.2x). No validated lever remains => practical ceiling.

#define D_MODEL 2048
#define BATCH   2048
#define NT      64
#define RANK    32

typedef __attribute__((ext_vector_type(8))) __bf16 bf16x8;
typedef __attribute__((ext_vector_type(4))) float  f32x4;
typedef __attribute__((ext_vector_type(8))) unsigned short ushort8;

__device__ __forceinline__ unsigned short f2bf(float f) {
  unsigned int u = __builtin_bit_cast(unsigned int, f);
  u += 0x7FFFu + ((u >> 16) & 1u);          // RNE
  return (unsigned short)(u >> 16);
}

// async global->LDS, 16B per lane. LDS dest is wave-uniform base + lane*16.
__device__ __forceinline__ void gload_lds16(const void* g, void* l) {
  __builtin_amdgcn_global_load_lds(
      (const __attribute__((address_space(1))) unsigned int*)g,
      (__attribute__((address_space(3))) unsigned int*)l,
      16, 0, 0);
}

// wait until <=N vector-memory ops outstanding, then workgroup barrier.
// Single asm block: no memory op can be scheduled between wait and barrier.
template <int N>
__device__ __forceinline__ void vm_wait_barrier() {
  if constexpr (N == 0)
    asm volatile("s_waitcnt vmcnt(0)\ns_barrier" ::: "memory");
  else if constexpr (N == 8)
    asm volatile("s_waitcnt vmcnt(8)\ns_barrier" ::: "memory");
  else if constexpr (N == 9)
    asm volatile("s_waitcnt vmcnt(9)\ns_barrier" ::: "memory");
  else
    static_assert(N == 0 || N == 8 || N == 9, "add vmcnt case");
}

// ---------------- merged prep ----------------
// blocks [0,1024): x->bf16   [1024,1152): enc->bf16
// blocks [1152,1408): V->bf16 (+sumsq)   [1408,1664): U->Ut bf16 (+sumsq)

__device__ __forceinline__ void block_reduce_store(float ss, float* dst, int slot) {
  __shared__ float red[256];
  int t = threadIdx.x;
  red[t] = ss;
  __syncthreads();
  for (int s = 128; s > 0; s >>= 1) {
    if (t < s) red[t] += red[t + s];
    __syncthreads();
  }
  if (t == 0) dst[slot] = red[0];
}

__global__ void k_prep(const float4* __restrict__ x, const float4* __restrict__ enc,
                       const float4* __restrict__ V, const float4* __restrict__ U,
                       ushort4* __restrict__ xb, ushort4* __restrict__ encb,
                       ushort4* __restrict__ Vb, unsigned short* __restrict__ Ut,
                       float* __restrict__ partV, float* __restrict__ partU) {
  int bid = blockIdx.x, t = threadIdx.x;
  if (bid < 1024) {                      // x: 1048576 float4, 1024 per block
#pragma unroll
    for (int it = 0; it < 4; ++it) {
      int i = bid * 1024 + it * 256 + t;
      float4 v = x[i];
      ushort4 o;
      o.x = f2bf(v.x); o.y = f2bf(v.y); o.z = f2bf(v.z); o.w = f2bf(v.w);
      xb[i] = o;
    }
  } else if (bid < 1152) {               // enc: 32768 float4
    int i = (bid - 1024) * 256 + t;
    float4 v = enc[i];
    ushort4 o;
    o.x = f2bf(v.x); o.y = f2bf(v.y); o.z = f2bf(v.z); o.w = f2bf(v.w);
    encb[i] = o;
  } else if (bid < 1408) {               // V: contiguous convert + sumsq
    int b = bid - 1152;                  // 256 blocks: n=b>>2, quarter=b&3
    size_t base4 = (size_t)b * 4096;
    float ss = 0.f;
    for (int it = 0; it < 16; ++it) {
      size_t idx = base4 + t + it * 256;
      float4 v = V[idx];
      ss += v.x * v.x + v.y * v.y + v.z * v.z + v.w * v.w;
      ushort4 o;
      o.x = f2bf(v.x); o.y = f2bf(v.y); o.z = f2bf(v.z); o.w = f2bf(v.w);
      Vb[idx] = o;
    }
    block_reduce_store(ss, partV, b);
  } else {                               // U: transpose-convert + sumsq, 16B stores
    int b = bid - 1408;
    int n = b >> 2;
    size_t base4 = (size_t)b * 4096;
    float ss = 0.f;
    for (int it = 0; it < 8; ++it) {
      size_t i2 = (size_t)(it * 256 + t) * 2;     // pair of consecutive float4
      size_t idx4 = base4 + i2;
      float4 v0 = U[idx4];
      float4 v1 = U[idx4 + 1];
      ss += v0.x * v0.x + v0.y * v0.y + v0.z * v0.z + v0.w * v0.w;
      ss += v1.x * v1.x + v1.y * v1.y + v1.z * v1.z + v1.w * v1.w;
      size_t e = idx4 * 4 - (size_t)n * (D_MODEL * RANK);  // elem offset in transform
      int dcol = (int)(e >> 5);
      int r = (int)(e & 31);              // 0,8,16,24 -> 16B aligned
      ushort8 o;
      o[0] = f2bf(v0.x); o[1] = f2bf(v0.y); o[2] = f2bf(v0.z); o[3] = f2bf(v0.w);
      o[4] = f2bf(v1.x); o[5] = f2bf(v1.y); o[6] = f2bf(v1.z); o[7] = f2bf(v1.w);
      *(ushort8*)(Ut + (size_t)dcol * 2048 + n * 32 + r) = o;
    }
    block_reduce_store(ss, partU, b);
  }
}

// ---------------- GEMM (BK=128, XOR-swizzled LDS, counted-vmcnt dbuf) -----
// A: M x K row-major bf16. Bt: N x K row-major bf16. VW = WGM*WGN waves.
// Row = 256B = 16 chunks of 16B; logical chunk cl at physical cl^(row&15).
// Pipeline depth 2, counted: stage(t+1) -> vmcnt(LPW) -> barrier ->
// compute tile t -> barrier. vmcnt never 0 in main loop (T4).
// EPI 0 (fused gate, needs WGM=2 WGN=4 MI=4 NJ=2): stage() adds a 4x128
//   enc tile (1KB, all waves duplicate-load so LPW uniform = 9). Per
//   K-step, wave (wm,wn) runs 4 extra MFMAs at s==wn: acc_g[i] +=
//   af[i] x enc-frag, accumulating pre-acts for rows wm*64+i*16+..,
//   n-local = lane&3 (cols 4-15 are dup of 0-3, ignored). Epilogue:
//   LDS-reduce acc_g over wn (wave wn's Y-cols have n-local == wn),
//   gate = relu(sum - bias), write out1 (l15==0 lanes) and gated bf16 Y.
//   Block 0 also finishes frob from partU/partV (ready: prep completed).
// EPI 1: outF[row*2048+col] = acc   (plain f32 store)
template <int WGM, int WGN, int MI, int NJ, int EPI, int SWZ>
__global__ __launch_bounds__(WGM * WGN * 64, 2)
void gemm_bt(const unsigned short* __restrict__ A,
             const unsigned short* __restrict__ Bt,
             unsigned short* __restrict__ outB,
             float* __restrict__ outF, int K, int klen,
             const unsigned short* __restrict__ Eb,
             const float* __restrict__ bias,
             const float* __restrict__ pU, const float* __restrict__ pV,
             float* __restrict__ frob, float* __restrict__ gateOut) {
  constexpr int VW = WGM * WGN;           // waves per block (multiple of 4)
  constexpr int BM = WGM * MI * 16;
  constexpr int BN = WGN * NJ * 16;
  constexpr int BK = 128;
  constexpr int GA = BM / (4 * VW);       // A stage instrs per wave per tile
  constexpr int GB = BN / (4 * VW);
  constexpr int LPW = GA + GB + (EPI == 0 ? 1 : 0);
  constexpr int HBUF = (BM + BN) * BK;    // shorts per buffer
  constexpr int ENCS = (EPI == 0) ? 512 : 0;  // shorts per enc buffer
  static_assert(EPI != 0 || (WGM == 2 && WGN == 4 && MI == 4 && NJ == 2),
                "EPI0 fused-gate layout requires 2x4 waves, MI=4, NJ=2");
  __shared__ __align__(16) unsigned short smem[2 * HBUF + 2 * ENCS];

  const int tid = threadIdx.x;
  const int w = tid >> 6;
  const int lane = tid & 63;
  const int quad = lane >> 4;
  const int l15 = lane & 15;
  const int wm = w % WGM;
  const int wn = w / WGM;

  int blockM, blockN;
  if constexpr (SWZ) {
    // grid.x = 256 = 16 (M/128) x 16 (N/128) tiles; lin%8 -> XCD,
    // each XCD owns a contiguous 4M x 8N tile region.
    const int lin = blockIdx.x;
    const int xcd = lin & 7;
    const int i = lin >> 3;              // 0..31 within XCD
    blockM = (xcd & 3) * 4 + (i & 3);    // [0,16)
    blockN = (xcd >> 2) * 8 + (i >> 2);  // [0,16)
  } else {
    blockN = blockIdx.x;
    blockM = blockIdx.y;
  }

  if constexpr (EPI == 0) {              // frob finish (inputs ready post-prep)
    if (blockIdx.x == 0 && tid < NT) {
      float su = pU[4 * tid] + pU[4 * tid + 1] + pU[4 * tid + 2] + pU[4 * tid + 3];
      float sv = pV[4 * tid] + pV[4 * tid + 1] + pV[4 * tid + 2] + pV[4 * tid + 3];
      frob[tid] = sqrtf(su) * sqrtf(sv) * (1.0f / 256.0f);
    }
  }

  // staging: instr (j,w) covers rows (j*VW+w)*4 + lrow4; key = row&15 =
  // (w&3)*4 + lrow4 (VW multiple of 4). Pre-swizzled source chunk lq.
  const int lrow4 = lane >> 4;
  const int key = ((w & 3) << 2) | lrow4;
  const int lq = l15 ^ key;
  const unsigned short* Ag = A + (size_t)(blockM * BM + w * 4 + lrow4) * K + lq * 8;
  const unsigned short* Bg = Bt + (size_t)(blockN * BN + w * 4 + lrow4) * K + lq * 8;
  // enc tile source: lane l covers n = bn*4 + (l>>4), k-chunk (l&15)*8
  const unsigned short* Eg = (EPI == 0)
      ? Eb + (size_t)(blockN * 4 + lrow4) * K + l15 * 8 : nullptr;

  // fragment rows rf have rf&15 == l15; physical chunk = (s*4+quad) ^ l15
  const int rfA = wm * MI * 16 + l15;
  const int rfB = wn * NJ * 16 + l15;

  f32x4 acc[MI][NJ];
  f32x4 acc_g[MI];
  const f32x4 z = {0.f, 0.f, 0.f, 0.f};
#pragma unroll
  for (int i = 0; i < MI; ++i) {
    acc_g[i] = z;
#pragma unroll
    for (int j = 0; j < NJ; ++j) acc[i][j] = z;
  }

  auto stage = [&](int buf, int k0) {
    unsigned short* As = smem + buf * HBUF;
    unsigned short* Bs = As + BM * BK;
#pragma unroll
    for (int j = 0; j < GA; ++j)
      gload_lds16(Ag + (size_t)(j * VW * 4) * K + k0,
                  (char*)As + (j * VW + w) * 1024);
#pragma unroll
    for (int j = 0; j < GB; ++j)
      gload_lds16(Bg + (size_t)(j * VW * 4) * K + k0,
                  (char*)Bs + (j * VW + w) * 1024);
    if constexpr (EPI == 0)              // all waves write same bytes: benign
      gload_lds16(Eg + k0, (char*)(smem + 2 * HBUF + buf * ENCS));
  };

  // prologue: stage K-tile 0 into buffer 0
  stage(0, 0);

  const int nt = klen / BK;
  int cur = 0;
  for (int t = 0; t < nt; ++t) {
    if (t + 1 < nt) {
      stage(cur ^ 1, (t + 1) * BK);      // issue next tile's loads
      vm_wait_barrier<LPW>();            // tile t landed; t+1 in flight
    } else {
      vm_wait_barrier<0>();              // last tile: drain
    }
    const unsigned short* As = smem + cur * HBUF;
    const unsigned short* Bs = As + BM * BK;
    const unsigned short* Es = smem + 2 * HBUF + cur * ENCS;
#pragma unroll
    for (int s = 0; s < 4; ++s) {
      bf16x8 af[MI], bfr[NJ];
#pragma unroll
      for (int i = 0; i < MI; ++i)
        af[i] = *(const bf16x8*)((const char*)As + (rfA + i * 16) * 256 +
                                 (((s * 4 + quad) ^ l15) << 4));
#pragma unroll
      for (int j = 0; j < NJ; ++j)
        bfr[j] = *(const bf16x8*)((const char*)Bs + (rfB + j * 16) * 256 +
                                  (((s * 4 + quad) ^ l15) << 4));
      if constexpr (EPI == 0) {
        if (s == wn) {                   // wave-uniform branch
          bf16x8 be = *(const bf16x8*)((const char*)Es +
                                       ((l15 & 3) * 128 + s * 32 + quad * 8) * 2);
#pragma unroll
          for (int i = 0; i < MI; ++i)
            acc_g[i] = __builtin_amdgcn_mfma_f32_16x16x32_bf16(af[i], be, acc_g[i], 0, 0, 0);
        }
      }
#pragma unroll
      for (int i = 0; i < MI; ++i)
#pragma unroll
        for (int j = 0; j < NJ; ++j)
          acc[i][j] = __builtin_amdgcn_mfma_f32_16x16x32_bf16(af[i], bfr[j], acc[i][j], 0, 0, 0);
    }
    // protect buffer reuse: next iter stages into the buffer just read.
    asm volatile("s_barrier" ::: "memory");
    cur ^= 1;
  }

  // epilogue: C/D layout col=lane&15, row=quad*4+reg
  const int row0 = blockM * BM + wm * MI * 16 + quad * 4;
  const int col0 = blockN * BN + wn * NJ * 16 + l15;
  if constexpr (EPI == 0) {
    // cross-wn reduce of gate partials: tmp[wn'][wm][i][r16][nl4] f32 (8KB,
    // staging LDS dead after final barrier).
    float* tmp = (float*)smem;
    if (l15 < 4) {
#pragma unroll
      for (int i = 0; i < MI; ++i)
#pragma unroll
        for (int r = 0; r < 4; ++r)
          tmp[(((wn * 2 + wm) * MI + i) * 16 + quad * 4 + r) * 4 + l15] = acc_g[i][r];
    }
    __syncthreads();
    const float bv = bias[blockN * 4 + wn];
#pragma unroll
    for (int i = 0; i < MI; ++i) {
#pragma unroll
      for (int t = 0; t < 4; ++t) {
        // this wave's Y-cols all have n-local == wn (wn*32 + j*16 + l15 < 128)
        float s0 = tmp[(((0 * 2 + wm) * MI + i) * 16 + quad * 4 + t) * 4 + wn]
                 + tmp[(((1 * 2 + wm) * MI + i) * 16 + quad * 4 + t) * 4 + wn]
                 + tmp[(((2 * 2 + wm) * MI + i) * 16 + quad * 4 + t) * 4 + wn]
                 + tmp[(((3 * 2 + wm) * MI + i) * 16 + quad * 4 + t) * 4 + wn];
        float pre = s0 - bv;
        float g = pre > 0.f ? pre : 0.f;
        const int row = row0 + i * 16 + t;
        if (l15 == 0)                     // unique (row, n) owner writes out1
          gateOut[(size_t)row * NT + blockN * 4 + wn] = g;
#pragma unroll
        for (int j = 0; j < NJ; ++j)
          outB[(size_t)row * 2048 + col0 + j * 16] = f2bf(acc[i][j][t] * g);
      }
    }
  } else {
#pragma unroll
    for (int i = 0; i < MI; ++i) {
#pragma unroll
      for (int j = 0; j < NJ; ++j) {
        const int col = col0 + j * 16;
#pragma unroll
        for (int t = 0; t < 4; ++t) {
          const int row = row0 + i * 16 + t;
          outF[(size_t)row * 2048 + col] = acc[i][j][t];
        }
      }
    }
  }
}

// ---------------- launch ----------------

extern "C" void kernel_launch(void* const* d_in, const int* in_sizes, int n_in,
                              void* d_out, int out_size, void* d_ws, size_t ws_size,
                              hipStream_t stream) {
  const float* x    = (const float*)d_in[0];
  const float* V    = (const float*)d_in[1];
  const float* U    = (const float*)d_in[2];
  const float* enc  = (const float*)d_in[3];
  const float* bias = (const float*)d_in[4];

  float* out  = (float*)d_out;                        // 2048*2048
  float* gate = out + (size_t)BATCH * D_MODEL;        // 2048*64
  float* frob = gate + (size_t)BATCH * NT;            // 64

  char* ws = (char*)d_ws;                             // ~33 MB used
  unsigned short* xb   = (unsigned short*)(ws);                     // 8 MB
  unsigned short* Vb   = (unsigned short*)(ws + (8u << 20));        // 8 MB
  unsigned short* Ut   = (unsigned short*)(ws + (16u << 20));       // 8 MB
  unsigned short* Yg   = (unsigned short*)(ws + (24u << 20));       // 8 MB
  unsigned short* encb = (unsigned short*)(ws + (32u << 20));       // 256 KB
  float* partU = (float*)(ws + (32u << 20) + 262144);
  float* partV = partU + 256;

  // prep: all bf16 conversions + U transpose + Frobenius partials
  k_prep<<<1664, 256, 0, stream>>>((const float4*)x, (const float4*)enc,
                                   (const float4*)V, (const float4*)U,
                                   (ushort4*)xb, (ushort4*)encb, (ushort4*)Vb, Ut,
                                   partV, partU);

  // G1' = fused: Yg = bf16(gate .* (x @ Vflat^T)), gate/out1, frob.
  // 2048^3 + 2048x64x2048, 128x128 tiles BK=128, 8 waves, 256 blocks
  // (1/CU), XCD-swizzled, counted-vmcnt depth-2 pipeline.
  gemm_bt<2, 4, 4, 2, 0, 1><<<dim3(256, 1, 1), 512, 0, stream>>>(
      xb, Vb, Yg, nullptr, D_MODEL, D_MODEL,
      encb, bias, partU, partV, frob, gate);

  // G2: out = Yg @ Ut^T: 2048^3, fp32 store, same GEMM structure
  gemm_bt<2, 4, 4, 2, 1, 1><<<dim3(256, 1, 1), 512, 0, stream>>>(
      Yg, Ut, nullptr, out, D_MODEL, D_MODEL,
      nullptr, nullptr, nullptr, nullptr, nullptr, nullptr);
}